// Round 1
// baseline (238.226 us; speedup 1.0000x reference)
//
#include <hip/hip_runtime.h>

typedef unsigned short u16;
typedef float   f32x4  __attribute__((ext_vector_type(4)));
typedef __bf16  bf16x8 __attribute__((ext_vector_type(8)));
typedef u16     u16x8  __attribute__((ext_vector_type(8)));

#define EMBED 1024
#define SEQ   2048
#define NB    2
#define NH    16
#define HD    64
#define MROWS 4096   // NB*SEQ

// ---- workspace layout (bytes) ----
// [0,8MB)   : 4x transposed weights, bf16 [N=1024][K=1024] each (Wq,Wk,Wv,Wo)
// [8,32MB)  : Xq,Xk,Xv bf16 [4096][1024]  (ctx reuses Xq region later)
// [32,40MB) : Qh  bf16 [B,H,S,D]  (pre-scaled by 1/8)
// [40,48MB) : Kh  bf16 [B,H,S,D]
// [48,56MB) : Vt  bf16 [B,H,D,S]
#define WS_WT  0u
#define WS_X   (8u<<20)
#define WS_QH  (32u<<20)
#define WS_KH  (40u<<20)
#define WS_VT  (48u<<20)
#define WS_CTX WS_X

__device__ __forceinline__ u16 f2bf(float f) {
  unsigned u = __builtin_bit_cast(unsigned, f);
  u += 0x7fffu + ((u >> 16) & 1u);          // RNE
  return (u16)(u >> 16);
}

__device__ __forceinline__ void gl16(const void* g, void* l) {
  __builtin_amdgcn_global_load_lds((__attribute__((address_space(1))) void*)g,
                                   (__attribute__((address_space(3))) void*)l,
                                   16, 0, 0);
}

// ---------------- pass 0a: fp32 -> bf16 ----------------
__global__ __launch_bounds__(256) void cvt_kernel(const float* __restrict__ q,
                                                  const float* __restrict__ k,
                                                  const float* __restrict__ v,
                                                  u16* __restrict__ X) {
  const float* src = blockIdx.z == 0 ? q : blockIdx.z == 1 ? k : v;
  u16* dst = X + (size_t)blockIdx.z * 4194304u;
  size_t i = ((size_t)blockIdx.x * 256 + threadIdx.x) * 8;
  f32x4 a = *(const f32x4*)(src + i);
  f32x4 b = *(const f32x4*)(src + i + 4);
  u16x8 o;
#pragma unroll
  for (int j = 0; j < 4; ++j) { o[j] = f2bf(a[j]); o[4 + j] = f2bf(b[j]); }
  *(u16x8*)(dst + i) = o;
}

// ---------------- pass 0b: W[K,N] fp32 -> Wt[N,K] bf16 ----------------
__global__ __launch_bounds__(256) void wtrans_kernel(const float* __restrict__ Wq,
                                                     const float* __restrict__ Wk,
                                                     const float* __restrict__ Wv,
                                                     const float* __restrict__ Wo,
                                                     u16* __restrict__ T) {
  const float* W = blockIdx.z == 0 ? Wq : blockIdx.z == 1 ? Wk : blockIdx.z == 2 ? Wv : Wo;
  u16* t = T + (size_t)blockIdx.z * 1048576u;
  __shared__ float sm[32][33];
  const int x = threadIdx.x, y = threadIdx.y;
  const int n0 = blockIdx.x * 32, k0 = blockIdx.y * 32;
#pragma unroll
  for (int i = 0; i < 4; ++i) sm[y + 8 * i][x] = W[(size_t)(k0 + y + 8 * i) * EMBED + n0 + x];
  __syncthreads();
#pragma unroll
  for (int i = 0; i < 4; ++i) t[(size_t)(n0 + y + 8 * i) * EMBED + k0 + x] = f2bf(sm[x][y + 8 * i]);
}

// ---------------- GEMM: C[M,N] = A[M,K] @ Wt^T + bias ----------------
// MODE 0: A = Xq/Xk/Xv (z), scatter epilogue to Qh/Kh/Vt (bf16)
// MODE 1: A = ctx, fp32 out + bias
template <int MODE>
__global__ __launch_bounds__(256) void gemm128(char* __restrict__ ws,
                                               const float* __restrict__ bias0,
                                               const float* __restrict__ bias1,
                                               const float* __restrict__ bias2,
                                               float* __restrict__ out) {
  const int z = (MODE == 0) ? blockIdx.z : 0;
  const u16* A  = (MODE == 0) ? (const u16*)(ws + WS_X) + (size_t)z * 4194304u
                              : (const u16*)(ws + WS_CTX);
  const u16* Bt = (const u16*)(ws + WS_WT) + (size_t)((MODE == 0) ? z : 3) * 1048576u;
  const float* bias = (MODE == 0) ? (z == 0 ? bias0 : z == 1 ? bias1 : bias2) : bias0;

  __shared__ u16 lA[128 * 32];
  __shared__ u16 lB[128 * 32];

  const int tid = threadIdx.x, l = tid & 63, w = tid >> 6, g = l >> 4, li = l & 15;
  const int m0 = blockIdx.y * 128, n0 = blockIdx.x * 128;
  const int wr = (w >> 1) * 64, wc = (w & 1) * 64;
  const int schunk = l & 3;

  f32x4 acc[4][4] = {};

  for (int kt = 0; kt < 32; ++kt) {
    const int k0 = kt * 32;
    // stage A tile [128][32] bf16, swizzled source so swizzled read is conflict-free
#pragma unroll
    for (int c = 0; c < 2; ++c) {
      const int ci = w * 2 + c;
      const int row = ci * 16 + (l >> 2);
      const int kk = (schunk ^ (row & 3)) * 8;
      gl16(A + (size_t)(m0 + row) * 1024 + k0 + kk, &lA[ci * 512 + l * 8]);
    }
#pragma unroll
    for (int c = 0; c < 2; ++c) {
      const int ci = w * 2 + c;
      const int row = ci * 16 + (l >> 2);
      const int kk = (schunk ^ (row & 3)) * 8;
      gl16(Bt + (size_t)(n0 + row) * 1024 + k0 + kk, &lB[ci * 512 + l * 8]);
    }
    __syncthreads();

    bf16x8 af[4], bfr[4];
#pragma unroll
    for (int mf = 0; mf < 4; ++mf) {
      const int r = wr + mf * 16 + li;
      af[mf] = __builtin_bit_cast(bf16x8, *(const u16x8*)&lA[r * 32 + (g ^ (r & 3)) * 8]);
    }
#pragma unroll
    for (int nf = 0; nf < 4; ++nf) {
      const int r = wc + nf * 16 + li;
      bfr[nf] = __builtin_bit_cast(bf16x8, *(const u16x8*)&lB[r * 32 + (g ^ (r & 3)) * 8]);
    }
#pragma unroll
    for (int mf = 0; mf < 4; ++mf)
#pragma unroll
      for (int nf = 0; nf < 4; ++nf)
        acc[mf][nf] = __builtin_amdgcn_mfma_f32_16x16x32_bf16(af[mf], bfr[nf], acc[mf][nf], 0, 0, 0);
    __syncthreads();
  }

  u16* Qh = (u16*)(ws + WS_QH);
  u16* Kh = (u16*)(ws + WS_KH);
  u16* Vt = (u16*)(ws + WS_VT);
#pragma unroll
  for (int mf = 0; mf < 4; ++mf)
#pragma unroll
    for (int nf = 0; nf < 4; ++nf)
#pragma unroll
      for (int r4 = 0; r4 < 4; ++r4) {
        const int row = m0 + wr + mf * 16 + g * 4 + r4;
        const int col = n0 + wc + nf * 16 + li;
        float v = acc[mf][nf][r4] + bias[col];
        if (MODE == 1) {
          out[(size_t)row * 1024 + col] = v;
        } else {
          const int bb = row >> 11, s = row & 2047, hh = col >> 6, d = col & 63;
          if (z == 0)      Qh[((size_t)(bb * 16 + hh) * SEQ + s) * HD + d] = f2bf(v * 0.125f);
          else if (z == 1) Kh[((size_t)(bb * 16 + hh) * SEQ + s) * HD + d] = f2bf(v);
          else             Vt[((size_t)(bb * 16 + hh) * HD + d) * SEQ + s] = f2bf(v);
        }
      }
}

// ---------------- pass 2: flash attention ----------------
__global__ __launch_bounds__(256) void attn_kernel(char* __restrict__ ws) {
  const u16* Qh = (const u16*)(ws + WS_QH);
  const u16* Kh = (const u16*)(ws + WS_KH);
  const u16* Vt = (const u16*)(ws + WS_VT);
  u16* ctx = (u16*)(ws + WS_CTX);

  const int tid = threadIdx.x, l = tid & 63, w = tid >> 6, g = l >> 4, li = l & 15;
  const int qt = blockIdx.x, bh = blockIdx.y;
  const u16* Qp = Qh + (size_t)bh * SEQ * HD;
  const u16* Kp = Kh + (size_t)bh * SEQ * HD;
  const u16* Vp = Vt + (size_t)bh * HD * SEQ;
  const int qbase = qt * 128 + w * 32;

  __shared__ u16 Plds[4][32][72];   // wave-private, padded (stride 72)

  bf16x8 qf[2][2];
#pragma unroll
  for (int rf = 0; rf < 2; ++rf)
#pragma unroll
    for (int kk = 0; kk < 2; ++kk)
      qf[rf][kk] = __builtin_bit_cast(bf16x8,
          *(const u16x8*)(Qp + (size_t)(qbase + rf * 16 + li) * HD + kk * 32 + 8 * g));

  f32x4 o[2][4] = {};
  float m[2][4], ls[2][4];
#pragma unroll
  for (int rf = 0; rf < 2; ++rf)
#pragma unroll
    for (int r = 0; r < 4; ++r) { m[rf][r] = -1e30f; ls[rf][r] = 0.f; }

  for (int kt = 0; kt < 32; ++kt) {
    // S = (Q/8) K^T  for 32 q-rows x 64 keys per wave
    f32x4 s[2][4] = {};
#pragma unroll
    for (int kk = 0; kk < 2; ++kk) {
      bf16x8 kf[4];
#pragma unroll
      for (int cf = 0; cf < 4; ++cf)
        kf[cf] = __builtin_bit_cast(bf16x8,
            *(const u16x8*)(Kp + (size_t)(kt * 64 + cf * 16 + li) * HD + kk * 32 + 8 * g));
#pragma unroll
      for (int rf = 0; rf < 2; ++rf)
#pragma unroll
        for (int cf = 0; cf < 4; ++cf)
          s[rf][cf] = __builtin_amdgcn_mfma_f32_16x16x32_bf16(qf[rf][kk], kf[cf], s[rf][cf], 0, 0, 0);
    }
    // online softmax (wave-parallel; reduce across 16-lane col groups)
#pragma unroll
    for (int rf = 0; rf < 2; ++rf)
#pragma unroll
      for (int r = 0; r < 4; ++r) {
        float mx = fmaxf(fmaxf(s[rf][0][r], s[rf][1][r]), fmaxf(s[rf][2][r], s[rf][3][r]));
        mx = fmaxf(mx, __shfl_xor(mx, 1));
        mx = fmaxf(mx, __shfl_xor(mx, 2));
        mx = fmaxf(mx, __shfl_xor(mx, 4));
        mx = fmaxf(mx, __shfl_xor(mx, 8));
        const float mn = fmaxf(m[rf][r], mx);
        const float esc = __expf(m[rf][r] - mn);
        m[rf][r] = mn;
        float rs = 0.f;
#pragma unroll
        for (int cf = 0; cf < 4; ++cf) {
          float p = __expf(s[rf][cf][r] - mn);
          s[rf][cf][r] = p;
          rs += p;
        }
        rs += __shfl_xor(rs, 1); rs += __shfl_xor(rs, 2);
        rs += __shfl_xor(rs, 4); rs += __shfl_xor(rs, 8);
        ls[rf][r] = ls[rf][r] * esc + rs;
#pragma unroll
        for (int df = 0; df < 4; ++df) o[rf][df][r] *= esc;
      }
    // P -> LDS (layout change C->A), fences for cross-lane visibility
    asm volatile("s_waitcnt lgkmcnt(0)" ::: "memory");
#pragma unroll
    for (int rf = 0; rf < 2; ++rf)
#pragma unroll
      for (int cf = 0; cf < 4; ++cf)
#pragma unroll
        for (int r = 0; r < 4; ++r)
          Plds[w][rf * 16 + g * 4 + r][cf * 16 + li] = f2bf(s[rf][cf][r]);
    asm volatile("s_waitcnt lgkmcnt(0)" ::: "memory");
    // O += P @ V  (V^T read directly from global: L2/L3-resident)
#pragma unroll
    for (int kk = 0; kk < 2; ++kk) {
      bf16x8 pf[2], vf[4];
#pragma unroll
      for (int rf = 0; rf < 2; ++rf)
        pf[rf] = __builtin_bit_cast(bf16x8, *(const u16x8*)&Plds[w][rf * 16 + li][kk * 32 + 8 * g]);
#pragma unroll
      for (int df = 0; df < 4; ++df)
        vf[df] = __builtin_bit_cast(bf16x8,
            *(const u16x8*)(Vp + (size_t)(df * 16 + li) * SEQ + kt * 64 + kk * 32 + 8 * g));
#pragma unroll
      for (int rf = 0; rf < 2; ++rf)
#pragma unroll
        for (int df = 0; df < 4; ++df)
          o[rf][df] = __builtin_amdgcn_mfma_f32_16x16x32_bf16(pf[rf], vf[df], o[rf][df], 0, 0, 0);
    }
  }
  // epilogue: ctx[b, s, h*64+d] = o / l   (bf16)
  const int bb = bh >> 4, hh = bh & 15;
#pragma unroll
  for (int rf = 0; rf < 2; ++rf)
#pragma unroll
    for (int r = 0; r < 4; ++r) {
      const float rl = 1.0f / ls[rf][r];
      const int srow = qbase + rf * 16 + g * 4 + r;
#pragma unroll
      for (int df = 0; df < 4; ++df)
        ctx[((size_t)bb * SEQ + srow) * EMBED + hh * 64 + df * 16 + li] = f2bf(o[rf][df][r] * rl);
    }
}

extern "C" void kernel_launch(void* const* d_in, const int* in_sizes, int n_in,
                              void* d_out, int out_size, void* d_ws, size_t ws_size,
                              hipStream_t stream) {
  const float* q   = (const float*)d_in[0];
  const float* kin = (const float*)d_in[1];
  const float* val = (const float*)d_in[2];
  const float* Wq  = (const float*)d_in[3];
  const float* bq  = (const float*)d_in[4];
  const float* Wk  = (const float*)d_in[5];
  const float* bk  = (const float*)d_in[6];
  const float* Wv  = (const float*)d_in[7];
  const float* bv  = (const float*)d_in[8];
  const float* Wo  = (const float*)d_in[9];
  const float* bo  = (const float*)d_in[10];
  char* ws = (char*)d_ws;
  float* out = (float*)d_out;

  cvt_kernel<<<dim3(2048, 1, 3), 256, 0, stream>>>(q, kin, val, (u16*)(ws + WS_X));
  wtrans_kernel<<<dim3(32, 32, 4), dim3(32, 8), 0, stream>>>(Wq, Wk, Wv, Wo, (u16*)(ws + WS_WT));
  gemm128<0><<<dim3(8, 32, 3), 256, 0, stream>>>(ws, bq, bk, bv, nullptr);
  attn_kernel<<<dim3(16, 32), 256, 0, stream>>>(ws);
  gemm128<1><<<dim3(8, 32, 1), 256, 0, stream>>>(ws, bo, nullptr, nullptr, out);
}

// Round 2
// 208.448 us; speedup vs baseline: 1.1429x; 1.1429x over previous
//
#include <hip/hip_runtime.h>

typedef unsigned short u16;
typedef unsigned int   u32;
typedef float   f32x4   __attribute__((ext_vector_type(4)));
typedef float   f32x16  __attribute__((ext_vector_type(16)));
typedef __bf16  bf16x8  __attribute__((ext_vector_type(8)));
typedef u16     u16x8   __attribute__((ext_vector_type(8)));
typedef u16     u16x4   __attribute__((ext_vector_type(4)));
typedef u32     u32x4   __attribute__((ext_vector_type(4)));

#define EMBED 1024
#define SEQ   2048
#define NH    16
#define HD    64

// ---- workspace layout (bytes) ----
#define WS_WT  0u          // 4x Wt bf16 [N=1024][K=1024]
#define WS_X   (8u<<20)    // Xq,Xk,Xv bf16 [4096][1024]; ctx reuses Xq
#define WS_QH  (32u<<20)   // Qh bf16 [B,H,S,D], pre-scaled by 0.125*log2(e)
#define WS_KH  (40u<<20)   // Kh bf16 [B,H,S,D]
#define WS_VT  (48u<<20)   // Vs bf16 [B,H,D,S'] with key bits2<->3 swapped
#define WS_CTX WS_X

__device__ __forceinline__ u16 f2bf(float f) {
  unsigned u = __builtin_bit_cast(unsigned, f);
  u += 0x7fffu + ((u >> 16) & 1u);          // RNE
  return (u16)(u >> 16);
}

__device__ __forceinline__ u32 cvtpk(float lo, float hi) {
  u32 r;
  asm("v_cvt_pk_bf16_f32 %0, %1, %2" : "=v"(r) : "v"(lo), "v"(hi));
  return r;
}

__device__ __forceinline__ void gl16(const void* g, void* l) {
  __builtin_amdgcn_global_load_lds((__attribute__((address_space(1))) void*)g,
                                   (__attribute__((address_space(3))) void*)l,
                                   16, 0, 0);
}

// ---------------- pass 0a: fp32 -> bf16 ----------------
__global__ __launch_bounds__(256) void cvt_kernel(const float* __restrict__ q,
                                                  const float* __restrict__ k,
                                                  const float* __restrict__ v,
                                                  u16* __restrict__ X) {
  const float* src = blockIdx.z == 0 ? q : blockIdx.z == 1 ? k : v;
  u16* dst = X + (size_t)blockIdx.z * 4194304u;
  size_t i = ((size_t)blockIdx.x * 256 + threadIdx.x) * 8;
  f32x4 a = *(const f32x4*)(src + i);
  f32x4 b = *(const f32x4*)(src + i + 4);
  u16x8 o;
#pragma unroll
  for (int j = 0; j < 4; ++j) { o[j] = f2bf(a[j]); o[4 + j] = f2bf(b[j]); }
  *(u16x8*)(dst + i) = o;
}

// ---------------- pass 0b: W[K,N] fp32 -> Wt[N,K] bf16 ----------------
__global__ __launch_bounds__(256) void wtrans_kernel(const float* __restrict__ Wq,
                                                     const float* __restrict__ Wk,
                                                     const float* __restrict__ Wv,
                                                     const float* __restrict__ Wo,
                                                     u16* __restrict__ T) {
  const float* W = blockIdx.z == 0 ? Wq : blockIdx.z == 1 ? Wk : blockIdx.z == 2 ? Wv : Wo;
  u16* t = T + (size_t)blockIdx.z * 1048576u;
  __shared__ float sm[32][33];
  const int x = threadIdx.x, y = threadIdx.y;
  const int n0 = blockIdx.x * 32, k0 = blockIdx.y * 32;
#pragma unroll
  for (int i = 0; i < 4; ++i) sm[y + 8 * i][x] = W[(size_t)(k0 + y + 8 * i) * EMBED + n0 + x];
  __syncthreads();
#pragma unroll
  for (int i = 0; i < 4; ++i) t[(size_t)(n0 + y + 8 * i) * EMBED + k0 + x] = f2bf(sm[x][y + 8 * i]);
}

// ---------------- GEMM: C[M,N] = A[M,K] @ Wt^T + bias ----------------
template <int MODE>
__global__ __launch_bounds__(256) void gemm128(char* __restrict__ ws,
                                               const float* __restrict__ bias0,
                                               const float* __restrict__ bias1,
                                               const float* __restrict__ bias2,
                                               float* __restrict__ out) {
  const int z = (MODE == 0) ? blockIdx.z : 0;
  const u16* A  = (MODE == 0) ? (const u16*)(ws + WS_X) + (size_t)z * 4194304u
                              : (const u16*)(ws + WS_CTX);
  const u16* Bt = (const u16*)(ws + WS_WT) + (size_t)((MODE == 0) ? z : 3) * 1048576u;
  const float* bias = (MODE == 0) ? (z == 0 ? bias0 : z == 1 ? bias1 : bias2) : bias0;

  __shared__ u16 lA[128 * 32];
  __shared__ u16 lB[128 * 32];

  const int tid = threadIdx.x, l = tid & 63, w = tid >> 6, g = l >> 4, li = l & 15;
  const int m0 = blockIdx.y * 128, n0 = blockIdx.x * 128;
  const int wr = (w >> 1) * 64, wc = (w & 1) * 64;
  const int schunk = l & 3;

  f32x4 acc[4][4] = {};

  for (int kt = 0; kt < 32; ++kt) {
    const int k0 = kt * 32;
#pragma unroll
    for (int c = 0; c < 2; ++c) {
      const int ci = w * 2 + c;
      const int row = ci * 16 + (l >> 2);
      const int kk = (schunk ^ (row & 3)) * 8;
      gl16(A + (size_t)(m0 + row) * 1024 + k0 + kk, &lA[ci * 512 + l * 8]);
    }
#pragma unroll
    for (int c = 0; c < 2; ++c) {
      const int ci = w * 2 + c;
      const int row = ci * 16 + (l >> 2);
      const int kk = (schunk ^ (row & 3)) * 8;
      gl16(Bt + (size_t)(n0 + row) * 1024 + k0 + kk, &lB[ci * 512 + l * 8]);
    }
    __syncthreads();

    bf16x8 af[4], bfr[4];
#pragma unroll
    for (int mf = 0; mf < 4; ++mf) {
      const int r = wr + mf * 16 + li;
      af[mf] = __builtin_bit_cast(bf16x8, *(const u16x8*)&lA[r * 32 + (g ^ (r & 3)) * 8]);
    }
#pragma unroll
    for (int nf = 0; nf < 4; ++nf) {
      const int r = wc + nf * 16 + li;
      bfr[nf] = __builtin_bit_cast(bf16x8, *(const u16x8*)&lB[r * 32 + (g ^ (r & 3)) * 8]);
    }
#pragma unroll
    for (int mf = 0; mf < 4; ++mf)
#pragma unroll
      for (int nf = 0; nf < 4; ++nf)
        acc[mf][nf] = __builtin_amdgcn_mfma_f32_16x16x32_bf16(af[mf], bfr[nf], acc[mf][nf], 0, 0, 0);
    __syncthreads();
  }

  u16* Qh = (u16*)(ws + WS_QH);
  u16* Kh = (u16*)(ws + WS_KH);
  u16* Vt = (u16*)(ws + WS_VT);
#pragma unroll
  for (int mf = 0; mf < 4; ++mf)
#pragma unroll
    for (int nf = 0; nf < 4; ++nf)
#pragma unroll
      for (int r4 = 0; r4 < 4; ++r4) {
        const int row = m0 + wr + mf * 16 + g * 4 + r4;
        const int col = n0 + wc + nf * 16 + li;
        float v = acc[mf][nf][r4] + bias[col];
        if (MODE == 1) {
          out[(size_t)row * 1024 + col] = v;
        } else {
          const int bb = row >> 11, s = row & 2047, hh = col >> 6, d = col & 63;
          if (z == 0)      Qh[((size_t)(bb * 16 + hh) * SEQ + s) * HD + d] = f2bf(v * 0.1803368801f); // 0.125*log2(e)
          else if (z == 1) Kh[((size_t)(bb * 16 + hh) * SEQ + s) * HD + d] = f2bf(v);
          else {
            const int ssw = (s & ~12) | ((s & 4) << 1) | ((s & 8) >> 1);   // key bits2<->3 swap
            Vt[((size_t)(bb * 16 + hh) * HD + d) * SEQ + ssw] = f2bf(v);
          }
        }
      }
}

// ---------------- pass 2: flash attention, swapped-operand in-register softmax ----------------
// 1 wave / block; wave owns 32 q-rows (q = qt*32 + lane&31, lanes l and l+32 share q).
// S^T = mfma32x32x16(Kfrag, Qfrag): lane holds S[key=(r&3)+8*(r>>2)+4*hi][q=lane&31].
// O^T = mfma32x32x16(Vfrag, Pfrag): lane holds O[d=(r&3)+8*(r>>2)+4*hi][q=lane&31].
__global__ __launch_bounds__(64) void attn_kernel(char* __restrict__ ws) {
  const u16* Qh = (const u16*)(ws + WS_QH);
  const u16* Kh = (const u16*)(ws + WS_KH);
  const u16* Vs = (const u16*)(ws + WS_VT);
  u16* ctx = (u16*)(ws + WS_CTX);

  const int l = threadIdx.x, l31 = l & 31, hi = l >> 5;

  // bijective XCD swizzle: 2048 blocks = 8 * 256; 4 heads' K/V per XCD (~2MB, L2-fits)
  const int id = blockIdx.y * 64 + blockIdx.x;
  const int sw = (id & 7) * 256 + (id >> 3);
  const int bh = sw >> 6, qt = sw & 63;

  const u16* Qp = Qh + (size_t)bh * SEQ * HD;
  const u16* Kp = Kh + (size_t)bh * SEQ * HD;
  const u16* Vp = Vs + (size_t)bh * HD * SEQ;
  const int q = qt * 32 + l31;

  bf16x8 qf[4];
#pragma unroll
  for (int kk = 0; kk < 4; ++kk)
    qf[kk] = __builtin_bit_cast(bf16x8, *(const u16x8*)(Qp + (size_t)q * HD + kk * 16 + 8 * hi));

  f32x16 o0 = {}, o1 = {};
  float m = -1e30f, ls = 0.f;

  u16x8 ka[8], kb[8];
#pragma unroll
  for (int g = 0; g < 2; ++g)
#pragma unroll
    for (int kk = 0; kk < 4; ++kk)
      ka[g * 4 + kk] = *(const u16x8*)(Kp + (size_t)(g * 32 + l31) * HD + kk * 16 + 8 * hi);

#define ATTN_BODY(KC, KN, T)                                                             \
  {                                                                                      \
    const int tn = ((T) + 1) & 31;                                                       \
    _Pragma("unroll")                                                                    \
    for (int g = 0; g < 2; ++g)                                                          \
      _Pragma("unroll")                                                                  \
      for (int kk = 0; kk < 4; ++kk)                                                     \
        KN[g * 4 + kk] = *(const u16x8*)(Kp + (size_t)(tn * 64 + g * 32 + l31) * HD +    \
                                         kk * 16 + 8 * hi);                              \
    f32x16 s0 = {}, s1 = {};                                                             \
    _Pragma("unroll")                                                                    \
    for (int kk = 0; kk < 4; ++kk)                                                       \
      s0 = __builtin_amdgcn_mfma_f32_32x32x16_bf16(                                      \
          __builtin_bit_cast(bf16x8, KC[kk]), qf[kk], s0, 0, 0, 0);                      \
    _Pragma("unroll")                                                                    \
    for (int kk = 0; kk < 4; ++kk)                                                       \
      s1 = __builtin_amdgcn_mfma_f32_32x32x16_bf16(                                      \
          __builtin_bit_cast(bf16x8, KC[4 + kk]), qf[kk], s1, 0, 0, 0);                  \
    u16x8 vf[2][2][2]; /* [g32][dtile][kk16] */                                          \
    _Pragma("unroll")                                                                    \
    for (int g = 0; g < 2; ++g)                                                          \
      _Pragma("unroll")                                                                  \
      for (int dt = 0; dt < 2; ++dt)                                                     \
        _Pragma("unroll")                                                                \
        for (int kk = 0; kk < 2; ++kk)                                                   \
          vf[g][dt][kk] = *(const u16x8*)(Vp + (size_t)(dt * 32 + l31) * SEQ +           \
                                          (T) * 64 + g * 32 + kk * 16 + 8 * hi);         \
    float pm[4] = {-1e30f, -1e30f, -1e30f, -1e30f};                                      \
    _Pragma("unroll")                                                                    \
    for (int r = 0; r < 16; ++r) {                                                       \
      pm[r & 3] = fmaxf(pm[r & 3], s0[r]);                                               \
      pm[r & 3] = fmaxf(pm[r & 3], s1[r]);                                               \
    }                                                                                    \
    float pmax = fmaxf(fmaxf(pm[0], pm[1]), fmaxf(pm[2], pm[3]));                        \
    pmax = fmaxf(pmax, __shfl_xor(pmax, 32));                                            \
    if (__any(pmax > m + 8.0f)) {                                                        \
      const float mn = fmaxf(m, pmax);                                                   \
      const float esc = __builtin_amdgcn_exp2f(m - mn);                                  \
      m = mn;                                                                            \
      ls *= esc;                                                                         \
      _Pragma("unroll")                                                                  \
      for (int r = 0; r < 16; ++r) { o0[r] *= esc; o1[r] *= esc; }                       \
    }                                                                                    \
    float p0[16], p1[16], sr[4] = {0.f, 0.f, 0.f, 0.f};                                  \
    _Pragma("unroll")                                                                    \
    for (int r = 0; r < 16; ++r) {                                                       \
      p0[r] = __builtin_amdgcn_exp2f(s0[r] - m);                                         \
      p1[r] = __builtin_amdgcn_exp2f(s1[r] - m);                                         \
      sr[r & 3] += p0[r] + p1[r];                                                        \
    }                                                                                    \
    float rs = (sr[0] + sr[1]) + (sr[2] + sr[3]);                                        \
    rs += __shfl_xor(rs, 32);                                                            \
    ls += rs;                                                                            \
    u32 pw[16];                                                                          \
    _Pragma("unroll")                                                                    \
    for (int t2 = 0; t2 < 8; ++t2) {                                                     \
      pw[t2] = cvtpk(p0[2 * t2], p0[2 * t2 + 1]);                                        \
      pw[8 + t2] = cvtpk(p1[2 * t2], p1[2 * t2 + 1]);                                    \
    }                                                                                    \
    _Pragma("unroll")                                                                    \
    for (int g = 0; g < 2; ++g)                                                          \
      _Pragma("unroll")                                                                  \
      for (int kk = 0; kk < 2; ++kk) {                                                   \
        u32x4 wv = {pw[g * 8 + kk * 4 + 0], pw[g * 8 + kk * 4 + 1],                      \
                    pw[g * 8 + kk * 4 + 2], pw[g * 8 + kk * 4 + 3]};                     \
        bf16x8 pf = __builtin_bit_cast(bf16x8, wv);                                      \
        o0 = __builtin_amdgcn_mfma_f32_32x32x16_bf16(                                    \
            __builtin_bit_cast(bf16x8, vf[g][0][kk]), pf, o0, 0, 0, 0);                  \
        o1 = __builtin_amdgcn_mfma_f32_32x32x16_bf16(                                    \
            __builtin_bit_cast(bf16x8, vf[g][1][kk]), pf, o1, 0, 0, 0);                  \
      }                                                                                  \
  }

  for (int tt = 0; tt < 16; ++tt) {
    ATTN_BODY(ka, kb, 2 * tt);
    ATTN_BODY(kb, ka, 2 * tt + 1);
  }
#undef ATTN_BODY

  const int bb = bh >> 4, hh = bh & 15;
  const float rl = 1.0f / ls;
  u16* cp = ctx + ((size_t)bb * SEQ + q) * EMBED + hh * 64;
#pragma unroll
  for (int rr = 0; rr < 4; ++rr) {
    u16x4 ov0, ov1;
#pragma unroll
    for (int j = 0; j < 4; ++j) {
      ov0[j] = f2bf(o0[rr * 4 + j] * rl);
      ov1[j] = f2bf(o1[rr * 4 + j] * rl);
    }
    *(u16x4*)(cp + rr * 8 + hi * 4) = ov0;
    *(u16x4*)(cp + 32 + rr * 8 + hi * 4) = ov1;
  }
}

extern "C" void kernel_launch(void* const* d_in, const int* in_sizes, int n_in,
                              void* d_out, int out_size, void* d_ws, size_t ws_size,
                              hipStream_t stream) {
  const float* q   = (const float*)d_in[0];
  const float* kin = (const float*)d_in[1];
  const float* val = (const float*)d_in[2];
  const float* Wq  = (const float*)d_in[3];
  const float* bq  = (const float*)d_in[4];
  const float* Wk  = (const float*)d_in[5];
  const float* bk  = (const float*)d_in[6];
  const float* Wv  = (const float*)d_in[7];
  const float* bv  = (const float*)d_in[8];
  const float* Wo  = (const float*)d_in[9];
  const float* bo  = (const float*)d_in[10];
  char* ws = (char*)d_ws;
  float* out = (float*)d_out;

  cvt_kernel<<<dim3(2048, 1, 3), 256, 0, stream>>>(q, kin, val, (u16*)(ws + WS_X));
  wtrans_kernel<<<dim3(32, 32, 4), dim3(32, 8), 0, stream>>>(Wq, Wk, Wv, Wo, (u16*)(ws + WS_WT));
  gemm128<0><<<dim3(8, 32, 3), 256, 0, stream>>>(ws, bq, bk, bv, nullptr);
  attn_kernel<<<dim3(64, 32), 64, 0, stream>>>(ws);
  gemm128<1><<<dim3(8, 32, 1), 256, 0, stream>>>(ws, bo, nullptr, nullptr, out);
}

// Round 7
// 208.374 us; speedup vs baseline: 1.1433x; 1.0004x over previous
//
#include <hip/hip_runtime.h>

typedef unsigned short u16;
typedef unsigned int   u32;
typedef float   f32x4   __attribute__((ext_vector_type(4)));
typedef float   f32x16  __attribute__((ext_vector_type(16)));
typedef __bf16  bf16x8  __attribute__((ext_vector_type(8)));
typedef u16     u16x8   __attribute__((ext_vector_type(8)));
typedef u16     u16x4   __attribute__((ext_vector_type(4)));
typedef u32     u32x4   __attribute__((ext_vector_type(4)));

#define EMBED 1024
#define SEQ   2048
#define NH    16
#define HD    64

// ---- workspace layout (bytes) ----
#define WS_WT  0u          // 4x Wt bf16 [N=1024][K=1024]
#define WS_X   (8u<<20)    // Xq,Xk,Xv bf16 [4096][1024]; ctx reuses Xq
#define WS_QH  (32u<<20)   // Qh bf16 [B,H,S,D], pre-scaled by 0.125*log2(e)
#define WS_KH  (40u<<20)   // Kh bf16 [B,H,S,D]
#define WS_VT  (48u<<20)   // Vs bf16 [B,H,D,S'] with key bits2<->3 swapped
#define WS_CTX WS_X

__device__ __forceinline__ u16 f2bf(float f) {
  unsigned u = __builtin_bit_cast(unsigned, f);
  u += 0x7fffu + ((u >> 16) & 1u);          // RNE
  return (u16)(u >> 16);
}

__device__ __forceinline__ u32 cvtpk(float lo, float hi) {
  u32 r;
  asm("v_cvt_pk_bf16_f32 %0, %1, %2" : "=v"(r) : "v"(lo), "v"(hi));
  return r;
}

__device__ __forceinline__ void gl16(const void* g, void* l) {
  __builtin_amdgcn_global_load_lds((__attribute__((address_space(1))) void*)g,
                                   (__attribute__((address_space(3))) void*)l,
                                   16, 0, 0);
}

// ---------------- pass 0a: fp32 -> bf16 ----------------
__global__ __launch_bounds__(256) void cvt_kernel(const float* __restrict__ q,
                                                  const float* __restrict__ k,
                                                  const float* __restrict__ v,
                                                  u16* __restrict__ X) {
  const float* src = blockIdx.z == 0 ? q : blockIdx.z == 1 ? k : v;
  u16* dst = X + (size_t)blockIdx.z * 4194304u;
  size_t i = ((size_t)blockIdx.x * 256 + threadIdx.x) * 8;
  f32x4 a = *(const f32x4*)(src + i);
  f32x4 b = *(const f32x4*)(src + i + 4);
  u16x8 o;
#pragma unroll
  for (int j = 0; j < 4; ++j) { o[j] = f2bf(a[j]); o[4 + j] = f2bf(b[j]); }
  *(u16x8*)(dst + i) = o;
}

// ---------------- pass 0b: W[K,N] fp32 -> Wt[N,K] bf16 ----------------
__global__ __launch_bounds__(256) void wtrans_kernel(const float* __restrict__ Wq,
                                                     const float* __restrict__ Wk,
                                                     const float* __restrict__ Wv,
                                                     const float* __restrict__ Wo,
                                                     u16* __restrict__ T) {
  const float* W = blockIdx.z == 0 ? Wq : blockIdx.z == 1 ? Wk : blockIdx.z == 2 ? Wv : Wo;
  u16* t = T + (size_t)blockIdx.z * 1048576u;
  __shared__ float sm[32][33];
  const int x = threadIdx.x, y = threadIdx.y;
  const int n0 = blockIdx.x * 32, k0 = blockIdx.y * 32;
#pragma unroll
  for (int i = 0; i < 4; ++i) sm[y + 8 * i][x] = W[(size_t)(k0 + y + 8 * i) * EMBED + n0 + x];
  __syncthreads();
#pragma unroll
  for (int i = 0; i < 4; ++i) t[(size_t)(n0 + y + 8 * i) * EMBED + k0 + x] = f2bf(sm[x][y + 8 * i]);
}

// ---------------- GEMM: C[M,N] = A[M,K] @ Wt^T + bias ----------------
template <int MODE>
__global__ __launch_bounds__(256) void gemm128(char* __restrict__ ws,
                                               const float* __restrict__ bias0,
                                               const float* __restrict__ bias1,
                                               const float* __restrict__ bias2,
                                               float* __restrict__ out) {
  const int z = (MODE == 0) ? blockIdx.z : 0;
  const u16* A  = (MODE == 0) ? (const u16*)(ws + WS_X) + (size_t)z * 4194304u
                              : (const u16*)(ws + WS_CTX);
  const u16* Bt = (const u16*)(ws + WS_WT) + (size_t)((MODE == 0) ? z : 3) * 1048576u;
  const float* bias = (MODE == 0) ? (z == 0 ? bias0 : z == 1 ? bias1 : bias2) : bias0;

  __shared__ u16 lA[128 * 32];
  __shared__ u16 lB[128 * 32];

  const int tid = threadIdx.x, l = tid & 63, w = tid >> 6, g = l >> 4, li = l & 15;
  const int m0 = blockIdx.y * 128, n0 = blockIdx.x * 128;
  const int wr = (w >> 1) * 64, wc = (w & 1) * 64;
  const int schunk = l & 3;

  f32x4 acc[4][4] = {};

  for (int kt = 0; kt < 32; ++kt) {
    const int k0 = kt * 32;
#pragma unroll
    for (int c = 0; c < 2; ++c) {
      const int ci = w * 2 + c;
      const int row = ci * 16 + (l >> 2);
      const int kk = (schunk ^ (row & 3)) * 8;
      gl16(A + (size_t)(m0 + row) * 1024 + k0 + kk, &lA[ci * 512 + l * 8]);
    }
#pragma unroll
    for (int c = 0; c < 2; ++c) {
      const int ci = w * 2 + c;
      const int row = ci * 16 + (l >> 2);
      const int kk = (schunk ^ (row & 3)) * 8;
      gl16(Bt + (size_t)(n0 + row) * 1024 + k0 + kk, &lB[ci * 512 + l * 8]);
    }
    __syncthreads();

    bf16x8 af[4], bfr[4];
#pragma unroll
    for (int mf = 0; mf < 4; ++mf) {
      const int r = wr + mf * 16 + li;
      af[mf] = __builtin_bit_cast(bf16x8, *(const u16x8*)&lA[r * 32 + (g ^ (r & 3)) * 8]);
    }
#pragma unroll
    for (int nf = 0; nf < 4; ++nf) {
      const int r = wc + nf * 16 + li;
      bfr[nf] = __builtin_bit_cast(bf16x8, *(const u16x8*)&lB[r * 32 + (g ^ (r & 3)) * 8]);
    }
#pragma unroll
    for (int mf = 0; mf < 4; ++mf)
#pragma unroll
      for (int nf = 0; nf < 4; ++nf)
        acc[mf][nf] = __builtin_amdgcn_mfma_f32_16x16x32_bf16(af[mf], bfr[nf], acc[mf][nf], 0, 0, 0);
    __syncthreads();
  }

  u16* Qh = (u16*)(ws + WS_QH);
  u16* Kh = (u16*)(ws + WS_KH);
  u16* Vt = (u16*)(ws + WS_VT);
#pragma unroll
  for (int mf = 0; mf < 4; ++mf)
#pragma unroll
    for (int nf = 0; nf < 4; ++nf)
#pragma unroll
      for (int r4 = 0; r4 < 4; ++r4) {
        const int row = m0 + wr + mf * 16 + g * 4 + r4;
        const int col = n0 + wc + nf * 16 + li;
        float v = acc[mf][nf][r4] + bias[col];
        if (MODE == 1) {
          out[(size_t)row * 1024 + col] = v;
        } else {
          const int bb = row >> 11, s = row & 2047, hh = col >> 6, d = col & 63;
          if (z == 0)      Qh[((size_t)(bb * 16 + hh) * SEQ + s) * HD + d] = f2bf(v * 0.1803368801f); // 0.125*log2(e)
          else if (z == 1) Kh[((size_t)(bb * 16 + hh) * SEQ + s) * HD + d] = f2bf(v);
          else {
            const int ssw = (s & ~12) | ((s & 4) << 1) | ((s & 8) >> 1);   // key bits2<->3 swap
            Vt[((size_t)(bb * 16 + hh) * HD + d) * SEQ + ssw] = f2bf(v);
          }
        }
      }
}

// ---------------- pass 2: flash attention, swapped-operand in-register softmax ----------------
// 1 wave / block; wave owns 32 q-rows (q = qt*32 + lane&31, lanes l and l+32 share q).
// S^T = mfma32x32x16(Kfrag, Qfrag): lane holds S[key=(r&3)+8*(r>>2)+4*hi][q=lane&31].
// O^T = mfma32x32x16(Vfrag, Pfrag): lane holds O[d=(r&3)+8*(r>>2)+4*hi][q=lane&31].
__global__ __launch_bounds__(64) void attn_kernel(char* __restrict__ ws) {
  const u16* Qh = (const u16*)(ws + WS_QH);
  const u16* Kh = (const u16*)(ws + WS_KH);
  const u16* Vs = (const u16*)(ws + WS_VT);
  u16* ctx = (u16*)(ws + WS_CTX);

  const int l = threadIdx.x, l31 = l & 31, hi = l >> 5;

  // bijective XCD swizzle: 2048 blocks = 8 * 256; 4 heads' K/V per XCD (~2MB, L2-fits)
  const int id = blockIdx.y * 64 + blockIdx.x;
  const int sw = (id & 7) * 256 + (id >> 3);
  const int bh = sw >> 6, qt = sw & 63;

  const u16* Qp = Qh + (size_t)bh * SEQ * HD;
  const u16* Kp = Kh + (size_t)bh * SEQ * HD;
  const u16* Vp = Vs + (size_t)bh * HD * SEQ;
  const int q = qt * 32 + l31;

  bf16x8 qf[4];
#pragma unroll
  for (int kk = 0; kk < 4; ++kk)
    qf[kk] = __builtin_bit_cast(bf16x8, *(const u16x8*)(Qp + (size_t)q * HD + kk * 16 + 8 * hi));

  f32x16 o0 = {}, o1 = {};
  float m = -1e30f, ls = 0.f;

  u16x8 ka[8], kb[8];
#pragma unroll
  for (int g = 0; g < 2; ++g)
#pragma unroll
    for (int kk = 0; kk < 4; ++kk)
      ka[g * 4 + kk] = *(const u16x8*)(Kp + (size_t)(g * 32 + l31) * HD + kk * 16 + 8 * hi);

#define ATTN_BODY(KC, KN, T)                                                             \
  {                                                                                      \
    const int tn = ((T) + 1) & 31;                                                       \
    _Pragma("unroll")                                                                    \
    for (int g = 0; g < 2; ++g)                                                          \
      _Pragma("unroll")                                                                  \
      for (int kk = 0; kk < 4; ++kk)                                                     \
        KN[g * 4 + kk] = *(const u16x8*)(Kp + (size_t)(tn * 64 + g * 32 + l31) * HD +    \
                                         kk * 16 + 8 * hi);                              \
    f32x16 s0 = {}, s1 = {};                                                             \
    _Pragma("unroll")                                                                    \
    for (int kk = 0; kk < 4; ++kk)                                                       \
      s0 = __builtin_amdgcn_mfma_f32_32x32x16_bf16(                                      \
          __builtin_bit_cast(bf16x8, KC[kk]), qf[kk], s0, 0, 0, 0);                      \
    _Pragma("unroll")                                                                    \
    for (int kk = 0; kk < 4; ++kk)                                                       \
      s1 = __builtin_amdgcn_mfma_f32_32x32x16_bf16(                                      \
          __builtin_bit_cast(bf16x8, KC[4 + kk]), qf[kk], s1, 0, 0, 0);                  \
    u16x8 vf[2][2][2]; /* [g32][dtile][kk16] */                                          \
    _Pragma("unroll")                                                                    \
    for (int g = 0; g < 2; ++g)                                                          \
      _Pragma("unroll")                                                                  \
      for (int dt = 0; dt < 2; ++dt)                                                     \
        _Pragma("unroll")                                                                \
        for (int kk = 0; kk < 2; ++kk)                                                   \
          vf[g][dt][kk] = *(const u16x8*)(Vp + (size_t)(dt * 32 + l31) * SEQ +           \
                                          (T) * 64 + g * 32 + kk * 16 + 8 * hi);         \
    float pm[4] = {-1e30f, -1e30f, -1e30f, -1e30f};                                      \
    _Pragma("unroll")                                                                    \
    for (int r = 0; r < 16; ++r) {                                                       \
      pm[r & 3] = fmaxf(pm[r & 3], s0[r]);                                               \
      pm[r & 3] = fmaxf(pm[r & 3], s1[r]);                                               \
    }                                                                                    \
    float pmax = fmaxf(fmaxf(pm[0], pm[1]), fmaxf(pm[2], pm[3]));                        \
    pmax = fmaxf(pmax, __shfl_xor(pmax, 32));                                            \
    if (__any(pmax > m + 8.0f)) {                                                        \
      const float mn = fmaxf(m, pmax);                                                   \
      const float esc = __builtin_amdgcn_exp2f(m - mn);                                  \
      m = mn;                                                                            \
      ls *= esc;                                                                         \
      _Pragma("unroll")                                                                  \
      for (int r = 0; r < 16; ++r) { o0[r] *= esc; o1[r] *= esc; }                       \
    }                                                                                    \
    float p0[16], p1[16], sr[4] = {0.f, 0.f, 0.f, 0.f};                                  \
    _Pragma("unroll")                                                                    \
    for (int r = 0; r < 16; ++r) {                                                       \
      p0[r] = __builtin_amdgcn_exp2f(s0[r] - m);                                         \
      p1[r] = __builtin_amdgcn_exp2f(s1[r] - m);                                         \
      sr[r & 3] += p0[r] + p1[r];                                                        \
    }                                                                                    \
    float rs = (sr[0] + sr[1]) + (sr[2] + sr[3]);                                        \
    rs += __shfl_xor(rs, 32);                                                            \
    ls += rs;                                                                            \
    u32 pw[16];                                                                          \
    _Pragma("unroll")                                                                    \
    for (int t2 = 0; t2 < 8; ++t2) {                                                     \
      pw[t2] = cvtpk(p0[2 * t2], p0[2 * t2 + 1]);                                        \
      pw[8 + t2] = cvtpk(p1[2 * t2], p1[2 * t2 + 1]);                                    \
    }                                                                                    \
    _Pragma("unroll")                                                                    \
    for (int g = 0; g < 2; ++g)                                                          \
      _Pragma("unroll")                                                                  \
      for (int kk = 0; kk < 2; ++kk) {                                                   \
        u32x4 wv = {pw[g * 8 + kk * 4 + 0], pw[g * 8 + kk * 4 + 1],                      \
                    pw[g * 8 + kk * 4 + 2], pw[g * 8 + kk * 4 + 3]};                     \
        bf16x8 pf = __builtin_bit_cast(bf16x8, wv);                                      \
        o0 = __builtin_amdgcn_mfma_f32_32x32x16_bf16(                                    \
            __builtin_bit_cast(bf16x8, vf[g][0][kk]), pf, o0, 0, 0, 0);                  \
        o1 = __builtin_amdgcn_mfma_f32_32x32x16_bf16(                                    \
            __builtin_bit_cast(bf16x8, vf[g][1][kk]), pf, o1, 0, 0, 0);                  \
      }                                                                                  \
  }

  for (int tt = 0; tt < 16; ++tt) {
    ATTN_BODY(ka, kb, 2 * tt);
    ATTN_BODY(kb, ka, 2 * tt + 1);
  }
#undef ATTN_BODY

  const int bb = bh >> 4, hh = bh & 15;
  const float rl = 1.0f / ls;
  u16* cp = ctx + ((size_t)bb * SEQ + q) * EMBED + hh * 64;
#pragma unroll
  for (int rr = 0; rr < 4; ++rr) {
    u16x4 ov0, ov1;
#pragma unroll
    for (int j = 0; j < 4; ++j) {
      ov0[j] = f2bf(o0[rr * 4 + j] * rl);
      ov1[j] = f2bf(o1[rr * 4 + j] * rl);
    }
    *(u16x4*)(cp + rr * 8 + hi * 4) = ov0;
    *(u16x4*)(cp + 32 + rr * 8 + hi * 4) = ov1;
  }
}

extern "C" void kernel_launch(void* const* d_in, const int* in_sizes, int n_in,
                              void* d_out, int out_size, void* d_ws, size_t ws_size,
                              hipStream_t stream) {
  const float* q   = (const float*)d_in[0];
  const float* kin = (const float*)d_in[1];
  const float* val = (const float*)d_in[2];
  const float* Wq  = (const float*)d_in[3];
  const float* bq  = (const float*)d_in[4];
  const float* Wk  = (const float*)d_in[5];
  const float* bk  = (const float*)d_in[6];
  const float* Wv  = (const float*)d_in[7];
  const float* bv  = (const float*)d_in[8];
  const float* Wo  = (const float*)d_in[9];
  const float* bo  = (const float*)d_in[10];
  char* ws = (char*)d_ws;
  float* out = (float*)d_out;

  cvt_kernel<<<dim3(2048, 1, 3), 256, 0, stream>>>(q, kin, val, (u16*)(ws + WS_X));
  wtrans_kernel<<<dim3(32, 32, 4), dim3(32, 8), 0, stream>>>(Wq, Wk, Wv, Wo, (u16*)(ws + WS_WT));
  gemm128<0><<<dim3(8, 32, 3), 256, 0, stream>>>(ws, bq, bk, bv, nullptr);
  attn_kernel<<<dim3(64, 32), 64, 0, stream>>>(ws);
  gemm128<1><<<dim3(8, 32, 1), 256, 0, stream>>>(ws, bo, nullptr, nullptr, out);
}